// Round 7
// baseline (130.568 us; speedup 1.0000x reference)
//
#include <hip/hip_runtime.h>

// NormalizePixelPts: out[f][d] = in[f][d] * scale(d), scale in {1, 1/1280, 1/720}.
// Best structure so far (R2): dense grid-stride sweep + LDS scale table = 101us.
// This round: attack MLP + occupancy.
//  - per-element f32 table (4180 entries, 16.7 KB; +2 pad so a quad starting at
//    d0<=4176 never overruns) -> 8 blocks/CU possible (vs 4 with 33 KB table)
//  - quad scales via two 8-B-aligned float2 LDS reads (d0 always even)
//  - counted main loop: 32 iters for ALL 524,288 threads (32*T = 16,777,216 <= n4),
//    no per-iter bound check, unroll 4 -> 4 global loads in flight
//  - tail: threads tid < n4 - 32*T = 335,872 do one extra iteration
//  - d0 advances by (4*T) mod 4178 = 3974 with a single wrap per iter

#define FEAT_DIM 4178
#define SPLIT    570
#define KBLK     285
#define TBL_N    4180
#define NBLOCKS  2048
#define NTHREADS (NBLOCKS * 256)   // 524,288
#define MAIN_ITERS 32              // 32*NTHREADS = 16,777,216
#define D0_STEP  3974              // (4*NTHREADS) % 4178
#define TAIL_N   335872            // n4 - MAIN_ITERS*NTHREADS

typedef float f4 __attribute__((ext_vector_type(4)));
typedef float f2 __attribute__((ext_vector_type(2)));

__device__ __forceinline__ float scale_for(int d) {
    const float inv_w = 1.0f / 1280.0f;
    const float inv_h = 1.0f / 720.0f;
    if (d < SPLIT) {
        int r = d % KBLK;
        if (r == 0 || r == 81 || r >= 164) return 1.0f;
        if (r <= 80) return ((r - 1) & 1) ? inv_h : inv_w;
        return ((r - 82) & 1) ? inv_h : inv_w;  // 82..163 incl. RH-LH pair
    }
    return ((d - 570) & 1) ? inv_h : inv_w;
}

__global__ void __launch_bounds__(256)
normalize_pixel_pts_kernel(const f4* __restrict__ in, f4* __restrict__ out) {
    __shared__ float tbl[TBL_N];   // 16,720 B

    for (int t = threadIdx.x; t < TBL_N; t += 256) {
        int d = t >= FEAT_DIM ? t - FEAT_DIM : t;
        tbl[t] = scale_for(d);
    }
    __syncthreads();

    const f2* tbl2 = (const f2*)tbl;

    int tid = blockIdx.x * 256 + threadIdx.x;          // 0 .. 524,287
    int d0 = (int)((4u * (unsigned)tid) % (unsigned)FEAT_DIM);  // even
    int i = tid;

    #pragma unroll 4
    for (int r = 0; r < MAIN_ITERS; ++r) {
        f4 v = in[i];
        int h = d0 >> 1;
        f2 a = tbl2[h];
        f2 b = tbl2[h + 1];
        v.x *= a.x; v.y *= a.y; v.z *= b.x; v.w *= b.y;
        out[i] = v;
        i += NTHREADS;
        d0 += D0_STEP;
        if (d0 >= FEAT_DIM) d0 -= FEAT_DIM;
    }

    if (tid < TAIL_N) {            // one extra iteration; i,d0 already advanced
        f4 v = in[i];
        int h = d0 >> 1;
        f2 a = tbl2[h];
        f2 b = tbl2[h + 1];
        v.x *= a.x; v.y *= a.y; v.z *= b.x; v.w *= b.y;
        out[i] = v;
    }
}

extern "C" void kernel_launch(void* const* d_in, const int* in_sizes, int n_in,
                              void* d_out, int out_size, void* d_ws, size_t ws_size,
                              hipStream_t stream) {
    const f4* in = (const f4*)d_in[0];
    f4* out = (f4*)d_out;
    // out_size = 68,452,352 -> n4 = 17,113,088 = 32*524,288 + 335,872.
    normalize_pixel_pts_kernel<<<NBLOCKS, 256, 0, stream>>>(in, out);
}

// Round 8
// 129.167 us; speedup vs baseline: 1.0109x; 1.0109x over previous
//
#include <hip/hip_runtime.h>

// NormalizePixelPts: out[f][d] = in[f][d] * scale(d), scale in {1, 1/1280, 1/720}.
// R2 structure (best, 101us) + MLP fix:
//  - f4 LDS table, 2089 entries (33.4 KB): lane-contiguous ds_read_b128, no
//    bank conflicts (R7's f2 split measured 2.1M conflict cycles - reverted)
//  - 1024 blocks = 4/CU, balanced, fully resident; table built once per block
//  - COUNTED main loop (65 iters for all 262,144 threads) + 73,728-thread tail;
//    no per-iter bound check -> #pragma unroll 8 gives 8 independent
//    global_load_dwordx4 in flight per wave (R2 had ~1 -> latency-bound)
//  - phase j advances by 262,144 mod 2089 = 1019, single branchless wrap

#define FEAT_DIM 4178
#define SPLIT    570
#define KBLK     285
#define HALF     2089                  // float4-phase period (prime)
#define NBLOCKS  1024
#define T        (NBLOCKS * 256)       // 262,144 threads
#define JSTEP    1019                  // T mod HALF
#define FULL_ITERS 65                  // 65*T = 17,039,360
#define TAIL_N   73728                 // n4 - 65*T

typedef float f4 __attribute__((ext_vector_type(4)));

__device__ __forceinline__ float scale_for(int d) {
    const float inv_w = 1.0f / 1280.0f;
    const float inv_h = 1.0f / 720.0f;
    if (d >= FEAT_DIM) d -= FEAT_DIM;   // callers pass d < 2*FEAT_DIM
    if (d < SPLIT) {
        int r = d % KBLK;
        if (r == 0 || r == 81 || r >= 164) return 1.0f;
        if (r <= 80) return ((r - 1) & 1) ? inv_h : inv_w;
        return ((r - 82) & 1) ? inv_h : inv_w;  // 82..163 incl. RH-LH pair
    }
    return ((d - 570) & 1) ? inv_h : inv_w;
}

__global__ void __launch_bounds__(256)
normalize_pixel_pts_kernel(const f4* __restrict__ in, f4* __restrict__ out) {
    __shared__ f4 tbl[HALF];   // 33,424 B -> 4 blocks/CU

    for (int t = threadIdx.x; t < HALF; t += 256) {
        int d0 = 4 * t;                        // <= 8352 < 2*FEAT_DIM
        if (d0 >= FEAT_DIM) d0 -= FEAT_DIM;    // even, <= 4176
        f4 s;
        s.x = scale_for(d0);
        s.y = scale_for(d0 + 1);
        s.z = scale_for(d0 + 2);               // wrap handled in scale_for
        s.w = scale_for(d0 + 3);
        tbl[t] = s;
    }
    __syncthreads();

    int tid = blockIdx.x * 256 + threadIdx.x;  // 0 .. 262,143
    int i = tid;
    int j = tid % HALF;                        // phase of float4 i

    #pragma unroll 8
    for (int r = 0; r < FULL_ITERS - 1; ++r) { // 64 iters, 8 loads in flight
        f4 v = in[i];
        f4 s = tbl[j];
        v *= s;
        out[i] = v;
        i += T;
        j += JSTEP; if (j >= HALF) j -= HALF;
    }
    {   // 65th iteration (all threads)
        f4 v = in[i];
        f4 s = tbl[j];
        v *= s;
        out[i] = v;
        i += T;
        j += JSTEP; if (j >= HALF) j -= HALF;
    }
    if (tid < TAIL_N) {                        // final partial sweep
        f4 v = in[i];
        f4 s = tbl[j];
        v *= s;
        out[i] = v;
    }
}

extern "C" void kernel_launch(void* const* d_in, const int* in_sizes, int n_in,
                              void* d_out, int out_size, void* d_ws, size_t ws_size,
                              hipStream_t stream) {
    const f4* in = (const f4*)d_in[0];
    f4* out = (f4*)d_out;
    // out_size = 68,452,352 -> n4 = 17,113,088 = 65*262,144 + 73,728.
    normalize_pixel_pts_kernel<<<NBLOCKS, 256, 0, stream>>>(in, out);
}

// Round 9
// 114.412 us; speedup vs baseline: 1.1412x; 1.1290x over previous
//
#include <hip/hip_runtime.h>

// NormalizePixelPts: out[f][d] = in[f][d] * scale(d), scale in {1, 1/1280, 1/720}.
// Final structure: reg-resident scale + full residency + zero tail.
//  - 2089 blocks x 128 threads = 267,392 threads; stride = 267,392 ≡ 0 (mod 2089)
//    -> each thread's float4-phase is LOOP-INVARIANT: scale quad computed once
//    into registers; inner loop = load / 4x mul / store / add only.
//  - 2089 x 2 = 4,178 waves, ALL co-resident (< 8,192 cap) -> no straggler wave
//    of leftover blocks (R5's +11us bug at 2089x256).
//  - n4 = 17,113,088 = 267,392 x 64 EXACTLY: counted 64-iter loop, no guard,
//    no tail. Each grid-iteration sweeps one contiguous 4.28 MB span.

#define FEAT_DIM 4178
#define SPLIT    570
#define KBLK     285
#define HALF     2089                 // float4-phase period (prime)
#define BLOCKS   2089
#define BLOCK_T  128
#define STRIDE   (BLOCKS * BLOCK_T)   // 267,392 ≡ 0 (mod 2089)
#define ITERS    64                   // n4 / STRIDE exactly

typedef float f4 __attribute__((ext_vector_type(4)));

__device__ __forceinline__ float scale_for(int d) {
    const float inv_w = 1.0f / 1280.0f;
    const float inv_h = 1.0f / 720.0f;
    if (d >= FEAT_DIM) d -= FEAT_DIM;   // callers pass d < 2*FEAT_DIM
    if (d < SPLIT) {
        int r = d % KBLK;
        if (r == 0 || r == 81 || r >= 164) return 1.0f;
        if (r <= 80) return ((r - 1) & 1) ? inv_h : inv_w;
        return ((r - 82) & 1) ? inv_h : inv_w;  // 82..163 incl. RH-LH pair
    }
    return ((d - 570) & 1) ? inv_h : inv_w;
}

__global__ void __launch_bounds__(BLOCK_T)
normalize_pixel_pts_kernel(const f4* __restrict__ in, f4* __restrict__ out) {
    int tid = blockIdx.x * BLOCK_T + threadIdx.x;   // 0 .. 267,391
    int p = tid % HALF;                             // phase, invariant under +=STRIDE

    // Per-thread scale quad, computed ONCE (off the hot path).
    int d0 = 4 * p;                        // <= 8352 < 2*FEAT_DIM
    if (d0 >= FEAT_DIM) d0 -= FEAT_DIM;    // even, <= 4176
    f4 s;
    s.x = scale_for(d0);
    s.y = scale_for(d0 + 1);
    s.z = scale_for(d0 + 2);               // wrap handled in scale_for
    s.w = scale_for(d0 + 3);

    int i = tid;                           // max 17,113,087 < 2^31
    #pragma unroll 4
    for (int r = 0; r < ITERS; ++r, i += STRIDE) {
        f4 v = in[i];
        v *= s;
        out[i] = v;
    }
}

extern "C" void kernel_launch(void* const* d_in, const int* in_sizes, int n_in,
                              void* d_out, int out_size, void* d_ws, size_t ws_size,
                              hipStream_t stream) {
    const f4* in = (const f4*)d_in[0];
    f4* out = (f4*)d_out;
    // out_size = 68,452,352 -> n4 = 17,113,088 = 267,392 * 64 exactly.
    normalize_pixel_pts_kernel<<<BLOCKS, BLOCK_T, 0, stream>>>(in, out);
}

// Round 10
// 114.237 us; speedup vs baseline: 1.1430x; 1.0015x over previous
//
#include <hip/hip_runtime.h>

// NormalizePixelPts: out[f][d] = in[f][d] * scale(d), scale in {1, 1/1280, 1/720}.
// R2 structure (proven best, 101us) with ONE change: 512-thread blocks.
//  - f4 LDS table (2089 entries, 33.4 KB), lane-contiguous ds_read_b128,
//    conflict-free; built once per block.
//  - 1024 blocks x 512 threads: still exactly 4 blocks/CU (balanced, LDS
//    133.7/160 KB) but 32 waves/CU instead of 16 -> 2x memory-level
//    parallelism to hide HBM latency (R2's 16 KB outstanding/CU was marginal
//    vs the ~10.3 KB minimum for 6.3 TB/s at ~1000cy latency).
//  - plain guarded grid-stride loop: every hand-unrolled/counted variant
//    (R4-R9) lost to the compiler's scheduling of this simple form.

#define FEAT_DIM 4178
#define SPLIT    570
#define KBLK     285
#define HALF     2089        // float4-phase period (prime)
#define BLOCK_T  512

typedef float f4 __attribute__((ext_vector_type(4)));

__device__ __forceinline__ float scale_for(int d) {
    const float inv_w = 1.0f / 1280.0f;
    const float inv_h = 1.0f / 720.0f;
    if (d >= FEAT_DIM) d -= FEAT_DIM;   // callers pass d < 2*FEAT_DIM
    if (d < SPLIT) {
        int r = d % KBLK;
        if (r == 0 || r == 81 || r >= 164) return 1.0f;
        if (r <= 80) return ((r - 1) & 1) ? inv_h : inv_w;
        return ((r - 82) & 1) ? inv_h : inv_w;  // 82..163 incl. RH-LH pair
    }
    return ((d - 570) & 1) ? inv_h : inv_w;
}

__global__ void __launch_bounds__(BLOCK_T)
normalize_pixel_pts_kernel(const f4* __restrict__ in, f4* __restrict__ out, int n4) {
    __shared__ f4 tbl[HALF];   // 33,424 B -> 4 blocks/CU at 512 threads

    for (int t = threadIdx.x; t < HALF; t += BLOCK_T) {
        int d0 = 4 * t;                        // <= 8352 < 2*FEAT_DIM
        if (d0 >= FEAT_DIM) d0 -= FEAT_DIM;    // even, <= 4176
        f4 s;
        s.x = scale_for(d0);
        s.y = scale_for(d0 + 1);
        s.z = scale_for(d0 + 2);               // wrap handled in scale_for
        s.w = scale_for(d0 + 3);
        tbl[t] = s;
    }
    __syncthreads();

    int idx = blockIdx.x * BLOCK_T + threadIdx.x;
    int stride = gridDim.x * BLOCK_T;
    int j = idx % HALF;            // phase of float4 idx
    int jstep = stride % HALF;
    for (int i = idx; i < n4; i += stride) {
        f4 v = in[i];
        f4 s = tbl[j];
        v *= s;
        out[i] = v;
        j += jstep;
        if (j >= HALF) j -= HALF;
    }
}

extern "C" void kernel_launch(void* const* d_in, const int* in_sizes, int n_in,
                              void* d_out, int out_size, void* d_ws, size_t ws_size,
                              hipStream_t stream) {
    const f4* in = (const f4*)d_in[0];
    f4* out = (f4*)d_out;
    int n4 = out_size / 4;         // 17,113,088

    const int grid = 1024;         // 4 blocks/CU, balanced, 32 waves/CU
    normalize_pixel_pts_kernel<<<grid, BLOCK_T, 0, stream>>>(in, out, n4);
}